// Round 4
// baseline (10888.545 us; speedup 1.0000x reference)
//
#include <hip/hip_runtime.h>
#include <hip/hip_fp16.h>

// Problem constants (match reference)
constexpr int NN = 100000;   // nodes
constexpr int EE = 3200000;  // edges
constexpr int NBINS = 782;   // ceil(NN / 128): bin = dst >> 7
constexpr int BINCAP = 5120; // mean 4092, sigma 64 -> +16 sigma safety
constexpr int CHUNK = 8192;  // edges per binning block
constexpr int NCHB = (EE + CHUNK - 1) / CHUNK;  // 391

// ---------------- pass A: counting-sort edges into 128-node bins ----------------
// packed entry: (src << 7) | (dst & 127)   (fits 24 bits)
__global__ __launch_bounds__(256) void k_binA(const int* __restrict__ src,
                                              const int* __restrict__ dst,
                                              int* __restrict__ cursor,
                                              unsigned int* __restrict__ binarr) {
  __shared__ int cnt[1024];   // per-bin counts (padded to 1024)
  __shared__ int off[1024];   // exclusive offsets within chunk
  __shared__ int gbase[NBINS];
  __shared__ int ssc[256];
  __shared__ unsigned int stag[CHUNK];
  int tid = threadIdx.x;
  int base = blockIdx.x * CHUNK;
  for (int i = tid; i < 1024; i += 256) cnt[i] = 0;
  __syncthreads();
  // phase 1: count bins
  for (int i = tid; i < CHUNK; i += 256) {
    int e = base + i;
    if (e < EE) atomicAdd(&cnt[dst[e] >> 7], 1);
  }
  __syncthreads();
  // phase 2: exclusive scan cnt[1024] -> off
  int t4 = tid * 4;
  int s0 = cnt[t4], s1 = cnt[t4 + 1], s2 = cnt[t4 + 2], s3 = cnt[t4 + 3];
  int tsum = s0 + s1 + s2 + s3;
  ssc[tid] = tsum;
  __syncthreads();
  for (int o = 1; o < 256; o <<= 1) {
    int x = (tid >= o) ? ssc[tid - o] : 0;
    __syncthreads();
    ssc[tid] += x;
    __syncthreads();
  }
  int ex = ssc[tid] - tsum;
  off[t4] = ex;
  off[t4 + 1] = ex + s0;
  off[t4 + 2] = ex + s0 + s1;
  off[t4 + 3] = ex + s0 + s1 + s2;
  __syncthreads();
  // reserve global space; reuse cnt as running staging cursor
  for (int b = tid; b < NBINS; b += 256) {
    int c = cnt[b];
    gbase[b] = c ? atomicAdd(&cursor[b], c) : 0;
    cnt[b] = off[b];
  }
  __syncthreads();
  // phase 3: place packed entries into staging (sorted by bin)
  for (int i = tid; i < CHUNK; i += 256) {
    int e = base + i;
    if (e < EE) {
      int d = dst[e];
      int b = d >> 7;
      int p = atomicAdd(&cnt[b], 1);
      stag[p] = ((unsigned int)src[e] << 7) | (unsigned int)(d & 127);
    }
  }
  __syncthreads();
  // phase 4: coalesced-ish write out; bin of index i via binary search in off
  int total = (base + CHUNK <= EE) ? CHUNK : (EE - base);
  for (int i = tid; i < total; i += 256) {
    int lo = 0, hi = NBINS - 1;
    while (lo < hi) {
      int mid = (lo + hi + 1) >> 1;
      if (off[mid] <= i) lo = mid;
      else hi = mid - 1;
    }
    binarr[(size_t)lo * BINCAP + gbase[lo] + (i - off[lo])] = stag[i];
  }
}

// ---------------- per-bin degree count -> dinv ----------------
__global__ __launch_bounds__(256) void k_dinvB(const unsigned int* __restrict__ binarr,
                                               const int* __restrict__ cursor,
                                               float* __restrict__ dinv) {
  __shared__ int cnt[128];
  int b = blockIdx.x, tid = threadIdx.x;
  if (tid < 128) cnt[tid] = 0;
  __syncthreads();
  int n = cursor[b];
  const unsigned int* p = binarr + (size_t)b * BINCAP;
  for (int i = tid; i < n; i += 256) atomicAdd(&cnt[p[i] & 127], 1);
  __syncthreads();
  int node = b * 128 + tid;
  if (tid < 128 && node < NN) dinv[node] = rsqrtf((float)(cnt[tid] + 1));
}

// ---------------- fc1: t0 = (x @ fc1_w + fc1_b) * dinv  (fp16 out) ----------------
__global__ __launch_bounds__(256) void k_fc1(const float* __restrict__ x,
                                             __half* __restrict__ t0,
                                             const float* __restrict__ W,
                                             const float* __restrict__ b,
                                             const float* __restrict__ dinv) {
  __shared__ float Ws[3 * 32];
  __shared__ float bs[32];
  int tid = threadIdx.x;
  if (tid < 96) Ws[tid] = W[tid];
  if (tid < 32) bs[tid] = b[tid];
  __syncthreads();
  int node = blockIdx.x * 8 + (tid >> 5);
  int f = tid & 31;
  if (node >= NN) return;
  float x0 = x[node * 3], x1 = x[node * 3 + 1], x2 = x[node * 3 + 2];
  float v = fmaf(x0, Ws[f], fmaf(x1, Ws[32 + f], fmaf(x2, Ws[64 + f], bs[f])));
  t0[node * 32 + f] = __float2half(v * dinv[node]);
}

// ---------------- A: t1 = relu( (Âgather32 t0) @ W1 + b1 ) * dinv ----------------
// acc layout [f][node] (32 x 128 f32, 16KB): atomic bank = node%32 (near-conflict-free)
__global__ __launch_bounds__(512) void k_A(const __half2* __restrict__ t0,
                                           __half2* __restrict__ t1,
                                           const unsigned int* __restrict__ binarr,
                                           const int* __restrict__ cursor,
                                           const float* __restrict__ dinv,
                                           const float* __restrict__ W1,
                                           const float* __restrict__ b1) {
  __shared__ float acc[32 * 128];
  __shared__ __half2 W1h[32 * 32];  // [k][m] -> cols 2m,2m+1
  __shared__ float b1s[64];
  int tid = threadIdx.x, b = blockIdx.x;
  for (int i = tid; i < 32 * 128; i += 512) acc[i] = 0.f;
  for (int i = tid; i < 32 * 32; i += 512) {
    int k = i >> 5, m = i & 31;
    W1h[i] = __floats2half2_rn(W1[k * 64 + 2 * m], W1[k * 64 + 2 * m + 1]);
  }
  if (tid < 64) b1s[tid] = b1[tid];
  __syncthreads();
  int n = cursor[b];
  const unsigned int* p = binarr + (size_t)b * BINCAP;
  int c = tid & 15, slot = tid >> 4;  // 32 edge-slots, 16 lanes each
#pragma unroll 4
  for (int i = slot; i < n; i += 32) {
    unsigned int e = p[i];
    int srcn = e >> 7, dl = e & 127;
    float2 v = __half22float2(t0[(size_t)srcn * 16 + c]);
    atomicAdd(&acc[(2 * c) * 128 + dl], v.x);
    atomicAdd(&acc[(2 * c + 1) * 128 + dl], v.y);
  }
  __syncthreads();
  // self + scale + GEMM: 4 threads/node, 16 outputs each
  int ln = tid >> 2, q = tid & 3;
  int node = b * 128 + ln;
  if (node >= NN) return;
  float dv = dinv[node];
  float a[16];
#pragma unroll
  for (int j = 0; j < 16; ++j) a[j] = b1s[q * 16 + j];
#pragma unroll
  for (int k = 0; k < 32; k += 2) {
    float2 tv = __half22float2(t0[(size_t)node * 16 + (k >> 1)]);
    float u0 = (acc[k * 128 + ln] + tv.x) * dv;
    float u1 = (acc[(k + 1) * 128 + ln] + tv.y) * dv;
#pragma unroll
    for (int jj = 0; jj < 8; ++jj) {
      float2 w0 = __half22float2(W1h[k * 32 + q * 8 + jj]);
      float2 w1 = __half22float2(W1h[(k + 1) * 32 + q * 8 + jj]);
      a[2 * jj] = fmaf(u0, w0.x, a[2 * jj]);
      a[2 * jj + 1] = fmaf(u0, w0.y, a[2 * jj + 1]);
      a[2 * jj] = fmaf(u1, w1.x, a[2 * jj]);
      a[2 * jj + 1] = fmaf(u1, w1.y, a[2 * jj + 1]);
    }
  }
  __half2* o = t1 + (size_t)node * 32 + q * 8;
#pragma unroll
  for (int jj = 0; jj < 8; ++jj)
    o[jj] = __float22half2_rn(make_float2(fmaxf(a[2 * jj], 0.f) * dv,
                                          fmaxf(a[2 * jj + 1], 0.f) * dv));
}

// ---------------- C: t3 = ( relu((Âgather64 t1) @ W2 + b2) @ W3 ) * dinv ----------
__global__ __launch_bounds__(512) void k_C(const __half2* __restrict__ t1,
                                           __half2* __restrict__ t3,
                                           const unsigned int* __restrict__ binarr,
                                           const int* __restrict__ cursor,
                                           const float* __restrict__ dinv,
                                           const float* __restrict__ W2,
                                           const float* __restrict__ b2,
                                           const float* __restrict__ W3) {
  __shared__ float acc[64 * 128];   // 32KB, [f][node]; reused for G1 after barrier
  __shared__ __half2 W2h[64 * 32];  // 8KB
  __shared__ __half2 W3h[64 * 16];  // 4KB
  __shared__ float b2s[64];
  int tid = threadIdx.x, b = blockIdx.x;
  for (int i = tid; i < 64 * 128; i += 512) acc[i] = 0.f;
  for (int i = tid; i < 64 * 32; i += 512) {
    int k = i >> 5, m = i & 31;
    W2h[i] = __floats2half2_rn(W2[k * 64 + 2 * m], W2[k * 64 + 2 * m + 1]);
  }
  for (int i = tid; i < 64 * 16; i += 512) {
    int k = i >> 4, m = i & 15;
    W3h[i] = __floats2half2_rn(W3[k * 32 + 2 * m], W3[k * 32 + 2 * m + 1]);
  }
  if (tid < 64) b2s[tid] = b2[tid];
  __syncthreads();
  int n = cursor[b];
  const unsigned int* p = binarr + (size_t)b * BINCAP;
  int c = tid & 31, slot = tid >> 5;  // 16 edge-slots, 32 lanes each
#pragma unroll 4
  for (int i = slot; i < n; i += 16) {
    unsigned int e = p[i];
    int srcn = e >> 7, dl = e & 127;
    float2 v = __half22float2(t1[(size_t)srcn * 32 + c]);
    atomicAdd(&acc[(2 * c) * 128 + dl], v.x);
    atomicAdd(&acc[(2 * c + 1) * 128 + dl], v.y);
  }
  __syncthreads();
  // stage1: G1 = relu(u @ W2 + b2); u computed on the fly; 4 threads/node x 16 outs
  int ln = tid >> 2, q = tid & 3;
  int node = b * 128 + ln;
  bool ok = node < NN;
  float dv = ok ? dinv[node] : 0.f;
  float g[16];
#pragma unroll
  for (int j = 0; j < 16; ++j) g[j] = b2s[q * 16 + j];
  if (ok) {
#pragma unroll 2
    for (int k = 0; k < 64; k += 2) {
      float2 sv = __half22float2(t1[(size_t)node * 32 + (k >> 1)]);
      float u0 = (acc[k * 128 + ln] + sv.x) * dv;
      float u1 = (acc[(k + 1) * 128 + ln] + sv.y) * dv;
#pragma unroll
      for (int jj = 0; jj < 8; ++jj) {
        float2 w0 = __half22float2(W2h[k * 32 + q * 8 + jj]);
        float2 w1 = __half22float2(W2h[(k + 1) * 32 + q * 8 + jj]);
        g[2 * jj] = fmaf(u0, w0.x, g[2 * jj]);
        g[2 * jj + 1] = fmaf(u0, w0.y, g[2 * jj + 1]);
        g[2 * jj] = fmaf(u1, w1.x, g[2 * jj]);
        g[2 * jj + 1] = fmaf(u1, w1.y, g[2 * jj + 1]);
      }
    }
  }
  __syncthreads();  // all stage-1 reads of acc complete
  if (ok) {
#pragma unroll
    for (int j = 0; j < 16; ++j) acc[(q * 16 + j) * 128 + ln] = fmaxf(g[j], 0.f);
  }
  __syncthreads();
  // stage2: t3 = (G1 @ W3) * dinv; 4 threads/node x 8 outs
  if (ok) {
    float a[8];
#pragma unroll
    for (int j = 0; j < 8; ++j) a[j] = 0.f;
#pragma unroll 4
    for (int k = 0; k < 64; ++k) {
      float G = acc[k * 128 + ln];
#pragma unroll
      for (int jj = 0; jj < 4; ++jj) {
        float2 w = __half22float2(W3h[k * 16 + q * 4 + jj]);
        a[2 * jj] = fmaf(G, w.x, a[2 * jj]);
        a[2 * jj + 1] = fmaf(G, w.y, a[2 * jj + 1]);
      }
    }
    __half2* o = t3 + (size_t)node * 16 + q * 4;
#pragma unroll
    for (int jj = 0; jj < 4; ++jj)
      o[jj] = __float22half2_rn(make_float2(a[2 * jj] * dv, a[2 * jj + 1] * dv));
  }
}

// ---------------- D: h3 = relu((Âgather32 t3) + b3); non-final: t0' = h3*dinv;
//                  final: out = h3 . fc2_w + fc2_b ----------------
template <bool FINAL>
__global__ __launch_bounds__(512) void k_D(const __half2* __restrict__ t3in,
                                           __half2* __restrict__ t0n,
                                           float* __restrict__ out,
                                           const unsigned int* __restrict__ binarr,
                                           const int* __restrict__ cursor,
                                           const float* __restrict__ dinv,
                                           const float* __restrict__ b3,
                                           const float* __restrict__ fc2w,
                                           const float* __restrict__ fc2b) {
  __shared__ float acc[32 * 128];  // 16KB, [f][node]
  int tid = threadIdx.x, b = blockIdx.x;
  for (int i = tid; i < 32 * 128; i += 512) acc[i] = 0.f;
  __syncthreads();
  int n = cursor[b];
  const unsigned int* p = binarr + (size_t)b * BINCAP;
  int c = tid & 15, slot = tid >> 4;
#pragma unroll 4
  for (int i = slot; i < n; i += 32) {
    unsigned int e = p[i];
    int srcn = e >> 7, dl = e & 127;
    float2 v = __half22float2(t3in[(size_t)srcn * 16 + c]);
    atomicAdd(&acc[(2 * c) * 128 + dl], v.x);
    atomicAdd(&acc[(2 * c + 1) * 128 + dl], v.y);
  }
  __syncthreads();
  int node0 = b * 128;
#pragma unroll
  for (int r = 0; r < 4; ++r) {
    int ln = (tid >> 4) + r * 32;
    int node = node0 + ln;
    if (node < NN) {
      float dv = dinv[node];
      float2 sv = __half22float2(t3in[(size_t)node * 16 + c]);
      float h0 = fmaxf(fmaf(acc[(2 * c) * 128 + ln] + sv.x, dv, b3[2 * c]), 0.f);
      float h1 = fmaxf(fmaf(acc[(2 * c + 1) * 128 + ln] + sv.y, dv, b3[2 * c + 1]), 0.f);
      if (!FINAL) {
        t0n[(size_t)node * 16 + c] =
            __float22half2_rn(make_float2(h0 * dv, h1 * dv));
      } else {
        float part = fmaf(h0, fc2w[2 * c], h1 * fc2w[2 * c + 1]);
#pragma unroll
        for (int off = 8; off > 0; off >>= 1) part += __shfl_down(part, off, 16);
        if (c == 0) out[node] = part + fc2b[0];
      }
    }
  }
}

extern "C" void kernel_launch(void* const* d_in, const int* in_sizes, int n_in,
                              void* d_out, int out_size, void* d_ws, size_t ws_size,
                              hipStream_t stream) {
  const float* x = (const float*)d_in[0];
  const int* ei = (const int*)d_in[1];
  const int* esrc = ei;
  const int* edst = ei + EE;
  const float* fc1_w = (const float*)d_in[2];
  const float* fc1_b = (const float*)d_in[3];
  const float* w1 = (const float*)d_in[4];
  const float* b1 = (const float*)d_in[5];
  const float* w2 = (const float*)d_in[6];
  const float* b2 = (const float*)d_in[7];
  const float* w3 = (const float*)d_in[8];
  const float* b3 = (const float*)d_in[9];
  const float* fc2_w = (const float*)d_in[10];
  const float* fc2_b = (const float*)d_in[11];

  char* p = (char*)d_ws;
  auto carve = [&](size_t bytes) {
    void* r = (void*)p;
    p += (bytes + 255) & ~(size_t)255;
    return r;
  };
  int* cursor = (int*)carve(NBINS * sizeof(int));
  unsigned int* binarr = (unsigned int*)carve((size_t)NBINS * BINCAP * 4);
  float* dinv = (float*)carve(NN * sizeof(float));
  __half* t32a = (__half*)carve((size_t)NN * 32 * sizeof(__half));
  __half* t64 = (__half*)carve((size_t)NN * 64 * sizeof(__half));
  __half* t32b = (__half*)carve((size_t)NN * 32 * sizeof(__half));

  hipMemsetAsync(cursor, 0, NBINS * sizeof(int), stream);

  k_binA<<<NCHB, 256, 0, stream>>>(esrc, edst, cursor, binarr);
  k_dinvB<<<NBINS, 256, 0, stream>>>(binarr, cursor, dinv);
  k_fc1<<<NN / 8, 256, 0, stream>>>(x, t32a, fc1_w, fc1_b, dinv);

  for (int it = 0; it < 4; ++it) {
    k_A<<<NBINS, 512, 0, stream>>>((const __half2*)t32a, (__half2*)t64, binarr,
                                   cursor, dinv, w1, b1);
    k_C<<<NBINS, 512, 0, stream>>>((const __half2*)t64, (__half2*)t32b, binarr,
                                   cursor, dinv, w2, b2, w3);
    if (it < 3) {
      k_D<false><<<NBINS, 512, 0, stream>>>((const __half2*)t32b, (__half2*)t32a,
                                            nullptr, binarr, cursor, dinv, b3,
                                            nullptr, nullptr);
    } else {
      k_D<true><<<NBINS, 512, 0, stream>>>((const __half2*)t32b, nullptr,
                                           (float*)d_out, binarr, cursor, dinv,
                                           b3, fc2_w, fc2_b);
    }
  }
}

// Round 5
// 802.032 us; speedup vs baseline: 13.5762x; 13.5762x over previous
//
#include <hip/hip_runtime.h>
#include <hip/hip_fp16.h>

// Problem constants (match reference)
constexpr int NN = 100000;   // nodes
constexpr int EE = 3200000;  // edges
constexpr int BLOCK = 256;
constexpr int NBINS = 782;   // ceil(NN / 128): bin = dst >> 7
constexpr int BINCAP = 5120; // mean 4092, sigma 64 -> +16 sigma safety
constexpr int CHUNK = 8192;  // edges per binning block
constexpr int NCHB = (EE + CHUNK - 1) / CHUNK;  // 391

// ---------------- pass A: counting-sort edges into 128-node bins ----------------
// packed entry: (src << 7) | (dst & 127)
__global__ __launch_bounds__(256) void k_binA(const int* __restrict__ src,
                                              const int* __restrict__ dst,
                                              int* __restrict__ cursor,
                                              unsigned int* __restrict__ binarr) {
  __shared__ int cnt[1024];   // per-bin counts (padded to 1024)
  __shared__ int off[1024];   // exclusive offsets within chunk
  __shared__ int gbase[NBINS];
  __shared__ int ssc[256];
  __shared__ unsigned int stag[CHUNK];
  int tid = threadIdx.x;
  int base = blockIdx.x * CHUNK;
  for (int i = tid; i < 1024; i += 256) cnt[i] = 0;
  __syncthreads();
  // phase 1: count bins
  for (int i = tid; i < CHUNK; i += 256) {
    int e = base + i;
    if (e < EE) atomicAdd(&cnt[dst[e] >> 7], 1);
  }
  __syncthreads();
  // phase 2: exclusive scan cnt[1024] -> off
  int t4 = tid * 4;
  int s0 = cnt[t4], s1 = cnt[t4 + 1], s2 = cnt[t4 + 2], s3 = cnt[t4 + 3];
  int tsum = s0 + s1 + s2 + s3;
  ssc[tid] = tsum;
  __syncthreads();
  for (int o = 1; o < 256; o <<= 1) {
    int x = (tid >= o) ? ssc[tid - o] : 0;
    __syncthreads();
    ssc[tid] += x;
    __syncthreads();
  }
  int ex = ssc[tid] - tsum;
  off[t4] = ex;
  off[t4 + 1] = ex + s0;
  off[t4 + 2] = ex + s0 + s1;
  off[t4 + 3] = ex + s0 + s1 + s2;
  __syncthreads();
  // reserve global space; reuse cnt as running staging cursor
  for (int b = tid; b < NBINS; b += 256) {
    int c = cnt[b];
    gbase[b] = c ? atomicAdd(&cursor[b], c) : 0;
    cnt[b] = off[b];
  }
  __syncthreads();
  // phase 3: place packed entries into staging (sorted by bin)
  for (int i = tid; i < CHUNK; i += 256) {
    int e = base + i;
    if (e < EE) {
      int d = dst[e];
      int b = d >> 7;
      int p = atomicAdd(&cnt[b], 1);
      stag[p] = ((unsigned int)src[e] << 7) | (unsigned int)(d & 127);
    }
  }
  __syncthreads();
  // phase 4: coalesced write out; bin of index i via binary search in off
  int total = (base + CHUNK <= EE) ? CHUNK : (EE - base);
  for (int i = tid; i < total; i += 256) {
    int lo = 0, hi = NBINS - 1;
    while (lo < hi) {
      int mid = (lo + hi + 1) >> 1;
      if (off[mid] <= i) lo = mid;
      else hi = mid - 1;
    }
    binarr[(size_t)lo * BINCAP + gbase[lo] + (i - off[lo])] = stag[i];
  }
}

// ---------------- scan of per-bin counts -> binbase[NBINS+1] ----------------
__global__ __launch_bounds__(256) void k_binscan(const int* __restrict__ cursor,
                                                 int* __restrict__ binbase) {
  __shared__ int s[256];
  int t = threadIdx.x;
  int v[4];
  int sum = 0;
#pragma unroll
  for (int j = 0; j < 4; ++j) {
    int i = t * 4 + j;
    v[j] = (i < NBINS) ? cursor[i] : 0;
    sum += v[j];
  }
  s[t] = sum;
  __syncthreads();
  for (int o = 1; o < 256; o <<= 1) {
    int x = (t >= o) ? s[t - o] : 0;
    __syncthreads();
    s[t] += x;
    __syncthreads();
  }
  int ex = s[t] - sum;
#pragma unroll
  for (int j = 0; j < 4; ++j) {
    int i = t * 4 + j;
    if (i < NBINS) {
      binbase[i] = ex;
      ex += v[j];
    }
  }
  if (t == 255) binbase[NBINS] = s[255];  // total == EE
}

// ---------------- per-bin: sort by node, emit CSR (coalesced) + dinv ----------------
__global__ __launch_bounds__(256) void k_binB(const unsigned int* __restrict__ binarr,
                                              const int* __restrict__ cursor,
                                              const int* __restrict__ binbase,
                                              int* __restrict__ rowptr,
                                              int* __restrict__ col,
                                              float* __restrict__ dinv) {
  __shared__ int cnt[128];
  __shared__ int off[128];
  __shared__ int cur[128];
  __shared__ unsigned int stag[BINCAP];
  int b = blockIdx.x, tid = threadIdx.x;
  if (tid < 128) cnt[tid] = 0;
  __syncthreads();
  int n = cursor[b];
  const unsigned int* p = binarr + (size_t)b * BINCAP;
  for (int i = tid; i < n; i += 256) atomicAdd(&cnt[p[i] & 127], 1);
  __syncthreads();
  int d = (tid < 128) ? cnt[tid] : 0;
  if (tid < 128) off[tid] = d;
  __syncthreads();
  for (int o = 1; o < 128; o <<= 1) {
    int x = 0;
    if (tid < 128 && tid >= o) x = off[tid - o];
    __syncthreads();
    if (tid < 128) off[tid] += x;
    __syncthreads();
  }
  int gb = binbase[b];
  if (tid < 128) {
    int ex = off[tid] - d;  // exclusive
    cur[tid] = ex;
    int node = b * 128 + tid;
    if (node < NN) {
      rowptr[node] = gb + ex;
      dinv[node] = rsqrtf((float)(d + 1));  // +1 self loop
    }
  }
  __syncthreads();
  for (int i = tid; i < n; i += 256) {
    unsigned int e = p[i];
    int pos = atomicAdd(&cur[e & 127], 1);
    stag[pos] = e >> 7;
  }
  __syncthreads();
  for (int i = tid; i < n; i += 256) col[gb + i] = (int)stag[i];
  if (b == 0 && tid == 0) rowptr[NN] = binbase[NBINS];
}

// ---------------- fc1: t0 = (x @ fc1_w + fc1_b) * dinv  (fp16 out) ----------------
__global__ __launch_bounds__(BLOCK) void k_fc1(const float* __restrict__ x,
                                               __half* __restrict__ t0,
                                               const float* __restrict__ W,
                                               const float* __restrict__ b,
                                               const float* __restrict__ dinv) {
  __shared__ float Ws[3 * 32];
  __shared__ float bs[32];
  int tid = threadIdx.x;
  if (tid < 96) Ws[tid] = W[tid];
  if (tid < 32) bs[tid] = b[tid];
  __syncthreads();
  int node = blockIdx.x * 8 + (tid >> 5);
  int f = tid & 31;
  if (node >= NN) return;
  float x0 = x[node * 3], x1 = x[node * 3 + 1], x2 = x[node * 3 + 2];
  float v = fmaf(x0, Ws[f], fmaf(x1, Ws[32 + f], fmaf(x2, Ws[64 + f], bs[f])));
  t0[node * 32 + f] = __float2half(v * dinv[node]);
}

// ---------------- A: t1 = relu( (S32(t0))*dinv @ W1 + b1 ) * dinv ----------------
// t0: fp16 [N][32] (pre-scaled). t1: fp16 [N][64]. 32 nodes/block.
__global__ __launch_bounds__(BLOCK) void k_A(const __half2* __restrict__ t0,
                                             __half2* __restrict__ t1,
                                             const int* __restrict__ rowptr,
                                             const int* __restrict__ col,
                                             const float* __restrict__ dinv,
                                             const float* __restrict__ W1,
                                             const float* __restrict__ b1) {
  __shared__ __half2 W1h[32 * 32];  // [k][m] -> cols 2m,2m+1  (4KB)
  __shared__ float b1s[64];
  __shared__ float Hs[32 * 33];     // padded stride 33
  int tid = threadIdx.x;
  for (int i = tid; i < 32 * 32; i += BLOCK) {
    int k = i >> 5, m = i & 31;
    W1h[i] = __floats2half2_rn(W1[k * 64 + 2 * m], W1[k * 64 + 2 * m + 1]);
  }
  if (tid < 64) b1s[tid] = b1[tid];
  __syncthreads();

  int tile = blockIdx.x;
  // ---- aggregation: 32 nodes in 2 passes of 16 node-groups, 16 lanes/node ----
  int c = tid & 15;
#pragma unroll
  for (int p = 0; p < 2; ++p) {
    int ln = p * 16 + (tid >> 4);
    int node = tile * 32 + ln;
    float2 acc = __half22float2(t0[(size_t)node * 16 + c]);  // self loop
    int beg = rowptr[node], end = rowptr[node + 1];
#pragma unroll 8
    for (int e = beg; e < end; ++e) {
      float2 v = __half22float2(t0[(size_t)col[e] * 16 + c]);
      acc.x += v.x;
      acc.y += v.y;
    }
    float dv = dinv[node];
    Hs[ln * 33 + 2 * c] = acc.x * dv;
    Hs[ln * 33 + 2 * c + 1] = acc.y * dv;
  }
  __syncthreads();
  // ---- stage: t1 = relu(Hs @ W1 + b1) * dinv, streamed straight to global ----
  {
    int n = tid >> 3, c8 = tid & 7;  // 8 threads/node, 8 outputs each
    int node = tile * 32 + n;
    float a[8];
#pragma unroll
    for (int j = 0; j < 8; ++j) a[j] = b1s[c8 * 8 + j];
#pragma unroll
    for (int k = 0; k < 32; ++k) {
      float h = Hs[n * 33 + k];
#pragma unroll
      for (int jj = 0; jj < 4; ++jj) {
        float2 w = __half22float2(W1h[k * 32 + c8 * 4 + jj]);
        a[2 * jj] = fmaf(h, w.x, a[2 * jj]);
        a[2 * jj + 1] = fmaf(h, w.y, a[2 * jj + 1]);
      }
    }
    float dv = dinv[node];
    __half2* o = t1 + (size_t)node * 32 + c8 * 4;
#pragma unroll
    for (int jj = 0; jj < 4; ++jj)
      o[jj] = __float22half2_rn(make_float2(fmaxf(a[2 * jj], 0.f) * dv,
                                            fmaxf(a[2 * jj + 1], 0.f) * dv));
  }
}

// ---------------- C: t3 = ( relu((S64(t1))*dinv @ W2 + b2) @ W3 ) * dinv ----------
// t1: fp16 [N][64] (pre-scaled). t3: fp16 [N][32]. 16 nodes/block.
__global__ __launch_bounds__(BLOCK) void k_C(const __half2* __restrict__ t1,
                                             __half2* __restrict__ t3,
                                             const int* __restrict__ rowptr,
                                             const int* __restrict__ col,
                                             const float* __restrict__ dinv,
                                             const float* __restrict__ W2,
                                             const float* __restrict__ b2,
                                             const float* __restrict__ W3) {
  __shared__ __half2 W2h[64 * 32];  // 8KB
  __shared__ __half2 W3h[64 * 16];  // 4KB
  __shared__ float b2s[64];
  __shared__ float H2[16 * 65];     // agg result (u = Â h1)
  __shared__ float G1[16 * 65];     // relu(u @ W2 + b2)
  int tid = threadIdx.x;
  for (int i = tid; i < 64 * 32; i += BLOCK) {
    int k = i >> 5, m = i & 31;
    W2h[i] = __floats2half2_rn(W2[k * 64 + 2 * m], W2[k * 64 + 2 * m + 1]);
  }
  for (int i = tid; i < 64 * 16; i += BLOCK) {
    int k = i >> 4, m = i & 15;
    W3h[i] = __floats2half2_rn(W3[k * 32 + 2 * m], W3[k * 32 + 2 * m + 1]);
  }
  if (tid < 64) b2s[tid] = b2[tid];
  __syncthreads();

  int tile = blockIdx.x;
  // ---- aggregation at F=64: 16 nodes in 2 passes of 8 node-groups, 32 lanes ----
  int c = tid & 31;
#pragma unroll
  for (int p = 0; p < 2; ++p) {
    int ln = p * 8 + (tid >> 5);
    int node = tile * 16 + ln;
    float2 acc = __half22float2(t1[(size_t)node * 32 + c]);  // self loop
    int beg = rowptr[node], end = rowptr[node + 1];
#pragma unroll 8
    for (int e = beg; e < end; ++e) {
      float2 v = __half22float2(t1[(size_t)col[e] * 32 + c]);
      acc.x += v.x;
      acc.y += v.y;
    }
    float dv = dinv[node];
    H2[ln * 65 + 2 * c] = acc.x * dv;
    H2[ln * 65 + 2 * c + 1] = acc.y * dv;
  }
  __syncthreads();
  // ---- stage1: G1 = relu(H2 @ W2 + b2) ----
  {
    int n = tid >> 4, q = tid & 15;  // 16 threads/node, 4 outputs each
    float a[4];
#pragma unroll
    for (int j = 0; j < 4; ++j) a[j] = b2s[q * 4 + j];
#pragma unroll
    for (int k = 0; k < 64; ++k) {
      float h = H2[n * 65 + k];
      float2 w0 = __half22float2(W2h[k * 32 + q * 2]);
      float2 w1 = __half22float2(W2h[k * 32 + q * 2 + 1]);
      a[0] = fmaf(h, w0.x, a[0]);
      a[1] = fmaf(h, w0.y, a[1]);
      a[2] = fmaf(h, w1.x, a[2]);
      a[3] = fmaf(h, w1.y, a[3]);
    }
#pragma unroll
    for (int j = 0; j < 4; ++j) G1[n * 65 + q * 4 + j] = fmaxf(a[j], 0.f);
  }
  __syncthreads();
  // ---- stage2: t3 = (G1 @ W3) * dinv ----
  {
    int n = tid >> 4, c16 = tid & 15;  // 16 threads/node, 2 outputs each
    int node = tile * 16 + n;
    float a0 = 0.f, a1 = 0.f;
#pragma unroll
    for (int k = 0; k < 64; ++k) {
      float h = G1[n * 65 + k];
      float2 w = __half22float2(W3h[k * 16 + c16]);
      a0 = fmaf(h, w.x, a0);
      a1 = fmaf(h, w.y, a1);
    }
    float dv = dinv[node];
    t3[(size_t)node * 16 + c16] = __float22half2_rn(make_float2(a0 * dv, a1 * dv));
  }
}

// ---------------- D: h3 = relu(S32(t3)*dinv + b3); non-final: t0' = h3*dinv;
//                  final: out = h3 . fc2_w + fc2_b ----------------
template <bool FINAL>
__global__ __launch_bounds__(BLOCK) void k_D(const __half2* __restrict__ t3,
                                             __half2* __restrict__ t0n,
                                             float* __restrict__ out,
                                             const int* __restrict__ rowptr,
                                             const int* __restrict__ col,
                                             const float* __restrict__ dinv,
                                             const float* __restrict__ b3,
                                             const float* __restrict__ fc2w,
                                             const float* __restrict__ fc2b) {
  int tid = threadIdx.x;
  int node = blockIdx.x * 16 + (tid >> 4);
  int c = tid & 15;
  if (node >= NN) return;
  float2 acc = __half22float2(t3[(size_t)node * 16 + c]);  // self loop
  int beg = rowptr[node], end = rowptr[node + 1];
#pragma unroll 8
  for (int e = beg; e < end; ++e) {
    float2 v = __half22float2(t3[(size_t)col[e] * 16 + c]);
    acc.x += v.x;
    acc.y += v.y;
  }
  float dv = dinv[node];
  float h0 = fmaxf(fmaf(acc.x, dv, b3[2 * c]), 0.f);
  float h1 = fmaxf(fmaf(acc.y, dv, b3[2 * c + 1]), 0.f);
  if (!FINAL) {
    t0n[(size_t)node * 16 + c] = __float22half2_rn(make_float2(h0 * dv, h1 * dv));
  } else {
    float part = fmaf(h0, fc2w[2 * c], h1 * fc2w[2 * c + 1]);
#pragma unroll
    for (int off = 8; off > 0; off >>= 1) part += __shfl_down(part, off, 16);
    if (c == 0) out[node] = part + fc2b[0];
  }
}

extern "C" void kernel_launch(void* const* d_in, const int* in_sizes, int n_in,
                              void* d_out, int out_size, void* d_ws, size_t ws_size,
                              hipStream_t stream) {
  const float* x = (const float*)d_in[0];
  const int* ei = (const int*)d_in[1];
  const int* esrc = ei;
  const int* edst = ei + EE;
  const float* fc1_w = (const float*)d_in[2];
  const float* fc1_b = (const float*)d_in[3];
  const float* w1 = (const float*)d_in[4];
  const float* b1 = (const float*)d_in[5];
  const float* w2 = (const float*)d_in[6];
  const float* b2 = (const float*)d_in[7];
  const float* w3 = (const float*)d_in[8];
  const float* b3 = (const float*)d_in[9];
  const float* fc2_w = (const float*)d_in[10];
  const float* fc2_b = (const float*)d_in[11];

  char* p = (char*)d_ws;
  auto carve = [&](size_t bytes) {
    void* r = (void*)p;
    p += (bytes + 255) & ~(size_t)255;
    return r;
  };
  int* cursor = (int*)carve(NBINS * sizeof(int));
  int* binbase = (int*)carve((NBINS + 1) * sizeof(int));
  unsigned int* binarr = (unsigned int*)carve((size_t)NBINS * BINCAP * 4);
  int* rowptr = (int*)carve((NN + 1) * sizeof(int));
  float* dinv = (float*)carve(NN * sizeof(float));
  int* col = (int*)carve(EE * sizeof(int));
  __half* t32a = (__half*)carve((size_t)NN * 32 * sizeof(__half));
  __half* t64 = (__half*)carve((size_t)NN * 64 * sizeof(__half));
  __half* t32b = (__half*)carve((size_t)NN * 32 * sizeof(__half));

  hipMemsetAsync(cursor, 0, NBINS * sizeof(int), stream);

  k_binA<<<NCHB, 256, 0, stream>>>(esrc, edst, cursor, binarr);
  k_binscan<<<1, 256, 0, stream>>>(cursor, binbase);
  k_binB<<<NBINS, 256, 0, stream>>>(binarr, cursor, binbase, rowptr, col, dinv);

  // t0 = (x @ fc1_w + fc1_b) * dinv
  k_fc1<<<NN / 8, BLOCK, 0, stream>>>(x, t32a, fc1_w, fc1_b, dinv);

  for (int it = 0; it < 4; ++it) {
    k_A<<<NN / 32, BLOCK, 0, stream>>>((const __half2*)t32a, (__half2*)t64,
                                       rowptr, col, dinv, w1, b1);
    k_C<<<NN / 16, BLOCK, 0, stream>>>((const __half2*)t64, (__half2*)t32b,
                                       rowptr, col, dinv, w2, b2, w3);
    if (it < 3) {
      k_D<false><<<NN / 16, BLOCK, 0, stream>>>(
          (const __half2*)t32b, (__half2*)t32a, nullptr, rowptr, col, dinv, b3,
          nullptr, nullptr);
    } else {
      k_D<true><<<NN / 16, BLOCK, 0, stream>>>(
          (const __half2*)t32b, nullptr, (float*)d_out, rowptr, col, dinv, b3,
          fc2_w, fc2_b);
    }
  }
}